// Round 2
// 7407.391 us; speedup vs baseline: 2.0181x; 2.0181x over previous
//
#include <hip/hip_runtime.h>
#include <hip/hip_bf16.h>
#include <math.h>

#define V 32000
#define E 512
#define H 1024
#define SQ 128
#define T 100
#define NB 256
#define NTI 256
#define NTA 512
#define NTB 512
#define GROWS 16    // 4096 gate rows / 256 blocks
#define FROWS 125   // 32000 fc rows / 256 blocks
#define NEG_BIG (-1e30f)

typedef unsigned int u32;
typedef unsigned long long u64;

struct WS {
  float gates[4*H];        // gate pre-activations for current step
  float h[H];              // hidden state (written by k_b block 0)
  float c[2][H];           // cell state, double-buffered by step parity
  float logits[V];         // raw logits of current step
  float pmax[NB];          // per-block max logit
  float psum[NB];          // per-block sum exp(logit - blockmax)
  u64   pkey[NB];          // per-block packed argmax key
};

__device__ __forceinline__ float wave_sum(float v){
  #pragma unroll
  for (int m = 32; m; m >>= 1) v += __shfl_xor(v, m, 64);
  return v;
}

__device__ __forceinline__ float dot4(float4 w, const float* v){
  return w.x*v[0] + w.y*v[1] + w.z*v[2] + w.w*v[3];
}

__global__ void __launch_bounds__(NTI) k_init(const float* __restrict__ hn,
                                              const float* __restrict__ cn,
                                              WS* __restrict__ ws){
  int tid = threadIdx.x;
  for (int j = tid; j < H; j += NTI){
    ws->h[j]    = hn[j];
    ws->c[0][j] = cn[j];
  }
  ws->pmax[tid] = NEG_BIG;
  ws->psum[tid] = 0.f;
  ws->pkey[tid] = 0ull;
}

// k_a(t): finalize step t-1 (logZ, logp writes, index, token decode), then gates for step t
__global__ void __launch_bounds__(NTA) k_a(const float* __restrict__ emb,
                                           const float* __restrict__ W_ih,
                                           const float* __restrict__ W_hh,
                                           const float* __restrict__ b_ih,
                                           const float* __restrict__ b_hh,
                                           WS* __restrict__ ws,
                                           float* __restrict__ out,
                                           int t){
  __shared__ float redf[NTA];
  __shared__ u64   redu[NTA];
  int b = blockIdx.x, tid = threadIdx.x;
  int wv = tid >> 6, ln = tid & 63;
  int tok = 2;  // SOS

  if (t > 0){
    // global logZ + argmax from 256 per-block partials (redundantly per block)
    // pad tids >= NB with identities: fmax(x,NEG_BIG)=x, x+0=x, max(key,0)=key
    float mb = (tid < NB) ? ws->pmax[tid] : NEG_BIG;
    float sb = (tid < NB) ? ws->psum[tid] : 0.f;
    u64   kb = (tid < NB) ? ws->pkey[tid] : 0ull;
    redf[tid] = mb; redu[tid] = kb; __syncthreads();
    for (int o = NTA/2; o; o >>= 1){
      if (tid < o){
        redf[tid] = fmaxf(redf[tid], redf[tid+o]);
        u64 a = redu[tid], c = redu[tid+o];
        redu[tid] = (a > c) ? a : c;
      }
      __syncthreads();
    }
    float m = redf[0];
    u64 key = redu[0];
    __syncthreads();
    redf[tid] = sb * expf(mb - m); __syncthreads();
    for (int o = NTA/2; o; o >>= 1){ if (tid < o) redf[tid] += redf[tid+o]; __syncthreads(); }
    float logZ = m + logf(fmaxf(redf[0], 1e-30f));

    tok = (int)(~(u32)key);              // low 32 bits hold ~row
    if ((u32)tok >= (u32)V) tok = 2;     // defensive: never read OOB embedding

    if (tid < FROWS){
      int row = b*FROWS + tid;
      out[(size_t)(t-1)*V + row] = ws->logits[row] - logZ;
    }
    if (b == 0 && tid == 0)
      out[(size_t)T*V + (t-1)] = (float)tok;   // indices chunk, stored as f32
  }

  if (t < T){
    // preload lane slices of x = emb[tok] (8 elems) and h (16 elems), reused across rows
    float xv[8], hv[16];
    {
      const float4* xp = (const float4*)(emb + (size_t)tok*E) + ln*2;
      float4 x0 = xp[0], x1 = xp[1];
      xv[0]=x0.x; xv[1]=x0.y; xv[2]=x0.z; xv[3]=x0.w;
      xv[4]=x1.x; xv[5]=x1.y; xv[6]=x1.z; xv[7]=x1.w;
      const float4* hp = (const float4*)(ws->h) + ln*4;
      float4 h0 = hp[0], h1 = hp[1], h2 = hp[2], h3 = hp[3];
      hv[0]=h0.x; hv[1]=h0.y; hv[2]=h0.z; hv[3]=h0.w;
      hv[4]=h1.x; hv[5]=h1.y; hv[6]=h1.z; hv[7]=h1.w;
      hv[8]=h2.x; hv[9]=h2.y; hv[10]=h2.z; hv[11]=h2.w;
      hv[12]=h3.x; hv[13]=h3.y; hv[14]=h3.z; hv[15]=h3.w;
    }
    // 8 waves, each handles a PAIR of the block's 16 gate rows; all 12 row-loads
    // issued back-to-back so they stay in flight together (MLP).
    int rl0 = wv*2;
    int row0 = b*GROWS + rl0, row1 = row0 + 1;
    const float4* ap0 = (const float4*)(W_ih + (size_t)row0*E) + ln*2;
    const float4* ap1 = (const float4*)(W_ih + (size_t)row1*E) + ln*2;
    const float4* wh0 = (const float4*)(W_hh + (size_t)row0*H) + ln*4;
    const float4* wh1 = (const float4*)(W_hh + (size_t)row1*H) + ln*4;
    float4 ia[2], ib[2], ha[4], hb[4];
    #pragma unroll
    for (int k = 0; k < 2; ++k) ia[k] = ap0[k];
    #pragma unroll
    for (int k = 0; k < 2; ++k) ib[k] = ap1[k];
    #pragma unroll
    for (int k = 0; k < 4; ++k) ha[k] = wh0[k];
    #pragma unroll
    for (int k = 0; k < 4; ++k) hb[k] = wh1[k];
    float acc0 = dot4(ia[0], xv) + dot4(ia[1], xv+4)
               + dot4(ha[0], hv) + dot4(ha[1], hv+4) + dot4(ha[2], hv+8) + dot4(ha[3], hv+12);
    float acc1 = dot4(ib[0], xv) + dot4(ib[1], xv+4)
               + dot4(hb[0], hv) + dot4(hb[1], hv+4) + dot4(hb[2], hv+8) + dot4(hb[3], hv+12);
    acc0 = wave_sum(acc0);
    acc1 = wave_sum(acc1);
    if (ln == 0){
      ws->gates[row0] = acc0 + b_ih[row0] + b_hh[row0];
      ws->gates[row1] = acc1 + b_ih[row1] + b_hh[row1];
    }
  }
}

// k_b(t): h2/c2 (redundant per block), scores+softmax+ctx (redundant), FC slice + partials
__global__ void __launch_bounds__(NTB) k_b(const float* __restrict__ enc,
                                           const float* __restrict__ W_fc,
                                           const float* __restrict__ b_fc,
                                           WS* __restrict__ ws,
                                           int t){
  __shared__ float concat[2*H];   // [0,H) = h2, [H,2H) = ctx
  __shared__ float sc[SQ];
  __shared__ float pw[SQ];
  __shared__ float lg[128];
  __shared__ float redf[NTB];
  __shared__ u64   redu[NTB];
  int b = blockIdx.x, tid = threadIdx.x;
  int wv = tid >> 6, ln = tid & 63;

  // phase 1: LSTM cell update (every block redundantly; block 0 persists h,c)
  {
    float c2v[2], h2v[2];
    #pragma unroll
    for (int k = 0; k < 2; ++k){
      int j = tid + k*NTB;
      float gi = ws->gates[j];
      float gf = ws->gates[H + j];
      float gg = ws->gates[2*H + j];
      float go = ws->gates[3*H + j];
      float co = ws->c[t & 1][j];
      float si = 1.f/(1.f + expf(-gi));
      float sf = 1.f/(1.f + expf(-gf));
      float tg = tanhf(gg);
      float so = 1.f/(1.f + expf(-go));
      float cn = sf*co + si*tg;
      float hn = so*tanhf(cn);
      c2v[k] = cn; h2v[k] = hn;
      concat[j] = hn;
    }
    if (b == 0){
      #pragma unroll
      for (int k = 0; k < 2; ++k){
        int j = tid + k*NTB;
        ws->c[(t+1) & 1][j] = c2v[k];
        ws->h[j] = h2v[k];
      }
    }
  }
  __syncthreads();

  // phase 2: attention scores = enc @ h2 (8 waves x 16 rows, paired for MLP)
  {
    float hv[16];
    #pragma unroll
    for (int k = 0; k < 16; ++k) hv[k] = concat[ln*16 + k];
    #pragma unroll
    for (int u = 0; u < 8; ++u){
      int s0 = wv*16 + u*2, s1 = s0 + 1;
      const float4* e0p = (const float4*)(enc + (size_t)s0*H) + ln*4;
      const float4* e1p = (const float4*)(enc + (size_t)s1*H) + ln*4;
      float4 e0[4], e1[4];
      #pragma unroll
      for (int k = 0; k < 4; ++k) e0[k] = e0p[k];
      #pragma unroll
      for (int k = 0; k < 4; ++k) e1[k] = e1p[k];
      float acc0 = dot4(e0[0], hv) + dot4(e0[1], hv+4) + dot4(e0[2], hv+8) + dot4(e0[3], hv+12);
      float acc1 = dot4(e1[0], hv) + dot4(e1[1], hv+4) + dot4(e1[2], hv+8) + dot4(e1[3], hv+12);
      acc0 = wave_sum(acc0);
      acc1 = wave_sum(acc1);
      if (ln == 0){ sc[s0] = acc0; sc[s1] = acc1; }
    }
  }
  __syncthreads();

  // phase 3: softmax over 128 scores
  {
    float v = (tid < SQ) ? sc[tid] : NEG_BIG;
    redf[tid] = v; __syncthreads();
    for (int o = NTB/2; o; o >>= 1){ if (tid < o) redf[tid] = fmaxf(redf[tid], redf[tid+o]); __syncthreads(); }
    float m = redf[0]; __syncthreads();
    float e = (tid < SQ) ? expf(v - m) : 0.f;
    redf[tid] = e; __syncthreads();
    for (int o = NTB/2; o; o >>= 1){ if (tid < o) redf[tid] += redf[tid+o]; __syncthreads(); }
    float S = redf[0];
    if (tid < SQ) pw[tid] = e / S;
  }
  __syncthreads();

  // phase 4: ctx[j] = sum_s pw[s] * enc[s][j]; 512 threads x 2 contiguous cols
  {
    float a0 = 0.f, a1 = 0.f;
    const float2* eb = (const float2*)enc + tid;   // cols [tid*2, tid*2+2)
    for (int s = 0; s < SQ; ++s){
      float2 e = eb[(size_t)s*(H/2)];
      float w = pw[s];
      a0 += w*e.x; a1 += w*e.y;
    }
    concat[H + tid*2 + 0] = a0;
    concat[H + tid*2 + 1] = a1;
  }
  __syncthreads();

  // phase 5: FC rows. 8 waves, each computes a PAIR of rows per iteration with
  // explicit 16-deep float4 load batches (MLP); concat slice lives in registers.
  {
    float cv[32];
    #pragma unroll
    for (int k = 0; k < 8; ++k)
      #pragma unroll
      for (int m = 0; m < 4; ++m)
        cv[k*4 + m] = concat[k*256 + ln*4 + m];

    for (int l = wv*2; l < FROWS; l += 16){
      int l1 = (l+1 < FROWS) ? l+1 : l;          // last pair of block: duplicate row
      int row0 = b*FROWS + l, row1 = b*FROWS + l1;
      const float4* wp0 = (const float4*)(W_fc + (size_t)row0*2048) + ln;
      const float4* wp1 = (const float4*)(W_fc + (size_t)row1*2048) + ln;
      float4 wb0[8], wb1[8];
      #pragma unroll
      for (int k = 0; k < 8; ++k) wb0[k] = wp0[(size_t)k*64];
      #pragma unroll
      for (int k = 0; k < 8; ++k) wb1[k] = wp1[(size_t)k*64];
      float acc0 = 0.f, acc1 = 0.f;
      #pragma unroll
      for (int k = 0; k < 8; ++k){
        acc0 += dot4(wb0[k], cv + k*4);
        acc1 += dot4(wb1[k], cv + k*4);
      }
      acc0 = wave_sum(acc0);
      acc1 = wave_sum(acc1);
      if (ln == 0){
        float a0 = acc0 + b_fc[row0];
        ws->logits[row0] = a0; lg[l] = a0;
        if (l1 != l){
          float a1 = acc1 + b_fc[row1];
          ws->logits[row1] = a1; lg[l1] = a1;
        }
      }
    }
  }
  __syncthreads();

  // phase 6: block-local max / sumexp / packed argmax key
  {
    float v = (tid < FROWS) ? lg[tid] : NEG_BIG;
    redf[tid] = v; __syncthreads();
    for (int o = NTB/2; o; o >>= 1){ if (tid < o) redf[tid] = fmaxf(redf[tid], redf[tid+o]); __syncthreads(); }
    float mb = redf[0]; __syncthreads();
    float e = (tid < FROWS) ? expf(v - mb) : 0.f;
    redf[tid] = e; __syncthreads();
    for (int o = NTB/2; o; o >>= 1){ if (tid < o) redf[tid] += redf[tid+o]; __syncthreads(); }
    float sb = redf[0];

    u64 key = 0ull;
    if (tid < FROWS){
      u32 u = __float_as_uint(v);
      u32 srt = (u >> 31) ? ~u : (u | 0x80000000u);   // monotone float->uint map
      key = ((u64)srt << 32) | (u32)(~(u32)(b*FROWS + tid));  // ties -> smaller row wins
    }
    redu[tid] = key; __syncthreads();
    for (int o = NTB/2; o; o >>= 1){ if (tid < o){ u64 a = redu[tid], c2 = redu[tid+o]; redu[tid] = a > c2 ? a : c2; } __syncthreads(); }

    if (tid == 0){
      ws->pmax[b] = mb;
      ws->psum[b] = sb;
      ws->pkey[b] = redu[0];
    }
  }
}

extern "C" void kernel_launch(void* const* d_in, const int* in_sizes, int n_in,
                              void* d_out, int out_size, void* d_ws, size_t ws_size,
                              hipStream_t stream){
  const float* hn   = (const float*)d_in[0];
  const float* cn   = (const float*)d_in[1];
  const float* enc  = (const float*)d_in[2];
  const float* emb  = (const float*)d_in[3];
  const float* W_ih = (const float*)d_in[4];
  const float* W_hh = (const float*)d_in[5];
  const float* b_ih = (const float*)d_in[6];
  const float* b_hh = (const float*)d_in[7];
  const float* W_fc = (const float*)d_in[8];
  const float* b_fc = (const float*)d_in[9];
  float* out = (float*)d_out;
  WS* ws = (WS*)d_ws;
  if (ws_size < sizeof(WS)) return;  // needs ~160 KB

  k_init<<<1, NTI, 0, stream>>>(hn, cn, ws);
  for (int t = 0; t <= T; ++t){
    k_a<<<NB, NTA, 0, stream>>>(emb, W_ih, W_hh, b_ih, b_hh, ws, out, t);
    if (t < T) k_b<<<NB, NTB, 0, stream>>>(enc, W_fc, b_fc, ws, t);
  }
}

// Round 3
// 6898.660 us; speedup vs baseline: 2.1669x; 1.0737x over previous
//
#include <hip/hip_runtime.h>
#include <hip/hip_bf16.h>
#include <math.h>

#define V 32000
#define E 512
#define H 1024
#define SQ 128
#define T 100
#define NB 256
#define NTI 256
#define NTA 512
#define NTB 512
#define GROWS 16    // 4096 gate rows / 256 blocks
#define FROWS 125   // 32000 fc rows / 256 blocks
#define NEG_BIG (-1e30f)

typedef unsigned int u32;
typedef unsigned long long u64;

struct WS {
  float gates[4*H];        // gate pre-activations for current step
  float h[H];              // hidden state (written by k_b block 0)
  float c[2][H];           // cell state, double-buffered by step parity
  float logits[V];         // raw logits of current step
  float pmax[NB];          // per-block max logit
  float psum[NB];          // per-block sum exp(logit - blockmax)
  u64   pkey[NB];          // per-block packed argmax key
};

__device__ __forceinline__ float wave_sum(float v){
  #pragma unroll
  for (int m = 32; m; m >>= 1) v += __shfl_xor(v, m, 64);
  return v;
}

__device__ __forceinline__ float wave_max(float v){
  #pragma unroll
  for (int m = 32; m; m >>= 1) v = fmaxf(v, __shfl_xor(v, m, 64));
  return v;
}

__device__ __forceinline__ u64 wave_max_u64(u64 v){
  #pragma unroll
  for (int m = 32; m; m >>= 1){
    u64 o = __shfl_xor(v, m, 64);
    v = (o > v) ? o : v;
  }
  return v;
}

__device__ __forceinline__ float dot4(float4 w, const float* v){
  return w.x*v[0] + w.y*v[1] + w.z*v[2] + w.w*v[3];
}

__global__ void __launch_bounds__(NTI) k_init(const float* __restrict__ hn,
                                              const float* __restrict__ cn,
                                              WS* __restrict__ ws){
  int tid = threadIdx.x;
  for (int j = tid; j < H; j += NTI){
    ws->h[j]    = hn[j];
    ws->c[0][j] = cn[j];
  }
  ws->pmax[tid] = NEG_BIG;
  ws->psum[tid] = 0.f;
  ws->pkey[tid] = 0ull;
}

// k_a(t): finalize step t-1 (logZ, logp writes, index, token decode), then gates for step t
__global__ void __launch_bounds__(NTA) k_a(const float* __restrict__ emb,
                                           const float* __restrict__ W_ih,
                                           const float* __restrict__ W_hh,
                                           const float* __restrict__ b_ih,
                                           const float* __restrict__ b_hh,
                                           WS* __restrict__ ws,
                                           float* __restrict__ out,
                                           int t){
  __shared__ float bc_logZ;
  __shared__ int   bc_tok;
  int b = blockIdx.x, tid = threadIdx.x;
  int wv = tid >> 6, ln = tid & 63;
  int tok = 2;  // SOS

  if (t > 0){
    // wave 0 reduces the 256 per-block partials via shuffles; 1 barrier total
    if (wv == 0){
      float mb0 = ws->pmax[ln],       mb1 = ws->pmax[ln+64];
      float mb2 = ws->pmax[ln+128],   mb3 = ws->pmax[ln+192];
      float sb0 = ws->psum[ln],       sb1 = ws->psum[ln+64];
      float sb2 = ws->psum[ln+128],   sb3 = ws->psum[ln+192];
      u64   kb0 = ws->pkey[ln],       kb1 = ws->pkey[ln+64];
      u64   kb2 = ws->pkey[ln+128],   kb3 = ws->pkey[ln+192];
      float m = wave_max(fmaxf(fmaxf(mb0, mb1), fmaxf(mb2, mb3)));
      float S = sb0*expf(mb0 - m) + sb1*expf(mb1 - m)
              + sb2*expf(mb2 - m) + sb3*expf(mb3 - m);
      S = wave_sum(S);
      u64 ka = (kb0 > kb1) ? kb0 : kb1;
      u64 kc = (kb2 > kb3) ? kb2 : kb3;
      u64 key = wave_max_u64((ka > kc) ? ka : kc);
      if (ln == 0){
        bc_logZ = m + logf(fmaxf(S, 1e-30f));
        int tk = (int)(~(u32)key);
        if ((u32)tk >= (u32)V) tk = 2;    // defensive
        bc_tok = tk;
      }
    }
    __syncthreads();
    float logZ = bc_logZ;
    tok = bc_tok;

    if (tid < FROWS){
      int row = b*FROWS + tid;
      out[(size_t)(t-1)*V + row] = ws->logits[row] - logZ;
    }
    if (b == 0 && tid == 0)
      out[(size_t)T*V + (t-1)] = (float)tok;   // indices chunk, stored as f32
  }

  if (t < T){
    // preload lane slices of x = emb[tok] (8 elems) and h (16 elems), reused across rows
    float xv[8], hv[16];
    {
      const float4* xp = (const float4*)(emb + (size_t)tok*E) + ln*2;
      float4 x0 = xp[0], x1 = xp[1];
      xv[0]=x0.x; xv[1]=x0.y; xv[2]=x0.z; xv[3]=x0.w;
      xv[4]=x1.x; xv[5]=x1.y; xv[6]=x1.z; xv[7]=x1.w;
      const float4* hp = (const float4*)(ws->h) + ln*4;
      float4 h0 = hp[0], h1 = hp[1], h2 = hp[2], h3 = hp[3];
      hv[0]=h0.x; hv[1]=h0.y; hv[2]=h0.z; hv[3]=h0.w;
      hv[4]=h1.x; hv[5]=h1.y; hv[6]=h1.z; hv[7]=h1.w;
      hv[8]=h2.x; hv[9]=h2.y; hv[10]=h2.z; hv[11]=h2.w;
      hv[12]=h3.x; hv[13]=h3.y; hv[14]=h3.z; hv[15]=h3.w;
    }
    // 8 waves, each handles a PAIR of the block's 16 gate rows; all 12 row-loads
    // issued back-to-back so they stay in flight together (MLP).
    int rl0 = wv*2;
    int row0 = b*GROWS + rl0, row1 = row0 + 1;
    const float4* ap0 = (const float4*)(W_ih + (size_t)row0*E) + ln*2;
    const float4* ap1 = (const float4*)(W_ih + (size_t)row1*E) + ln*2;
    const float4* wh0 = (const float4*)(W_hh + (size_t)row0*H) + ln*4;
    const float4* wh1 = (const float4*)(W_hh + (size_t)row1*H) + ln*4;
    float4 ia[2], ib[2], ha[4], hb[4];
    #pragma unroll
    for (int k = 0; k < 2; ++k) ia[k] = ap0[k];
    #pragma unroll
    for (int k = 0; k < 2; ++k) ib[k] = ap1[k];
    #pragma unroll
    for (int k = 0; k < 4; ++k) ha[k] = wh0[k];
    #pragma unroll
    for (int k = 0; k < 4; ++k) hb[k] = wh1[k];
    float acc0 = dot4(ia[0], xv) + dot4(ia[1], xv+4)
               + dot4(ha[0], hv) + dot4(ha[1], hv+4) + dot4(ha[2], hv+8) + dot4(ha[3], hv+12);
    float acc1 = dot4(ib[0], xv) + dot4(ib[1], xv+4)
               + dot4(hb[0], hv) + dot4(hb[1], hv+4) + dot4(hb[2], hv+8) + dot4(hb[3], hv+12);
    acc0 = wave_sum(acc0);
    acc1 = wave_sum(acc1);
    if (ln == 0){
      ws->gates[row0] = acc0 + b_ih[row0] + b_hh[row0];
      ws->gates[row1] = acc1 + b_ih[row1] + b_hh[row1];
    }
  }
}

// k_b(t): h2/c2 (redundant per block), scores+softmax+ctx (redundant), FC slice + partials
__global__ void __launch_bounds__(NTB) k_b(const float* __restrict__ enc,
                                           const float* __restrict__ W_fc,
                                           const float* __restrict__ b_fc,
                                           WS* __restrict__ ws,
                                           int t){
  __shared__ float concat[2*H];   // [0,H) = h2, [H,2H) = ctx
  __shared__ float sc[SQ];
  __shared__ float pw[SQ];
  __shared__ float lg[128];
  int b = blockIdx.x, tid = threadIdx.x;
  int wv = tid >> 6, ln = tid & 63;

  // phase 1: LSTM cell update (every block redundantly; block 0 persists h,c)
  {
    float c2v[2], h2v[2];
    #pragma unroll
    for (int k = 0; k < 2; ++k){
      int j = tid + k*NTB;
      float gi = ws->gates[j];
      float gf = ws->gates[H + j];
      float gg = ws->gates[2*H + j];
      float go = ws->gates[3*H + j];
      float co = ws->c[t & 1][j];
      float si = 1.f/(1.f + expf(-gi));
      float sf = 1.f/(1.f + expf(-gf));
      float tg = tanhf(gg);
      float so = 1.f/(1.f + expf(-go));
      float cn = sf*co + si*tg;
      float hn = so*tanhf(cn);
      c2v[k] = cn; h2v[k] = hn;
      concat[j] = hn;
    }
    if (b == 0){
      #pragma unroll
      for (int k = 0; k < 2; ++k){
        int j = tid + k*NTB;
        ws->c[(t+1) & 1][j] = c2v[k];
        ws->h[j] = h2v[k];
      }
    }
  }
  __syncthreads();

  // phase 2: attention scores = enc @ h2 (8 waves x 16 rows, paired for MLP)
  {
    float hv[16];
    #pragma unroll
    for (int k = 0; k < 16; ++k) hv[k] = concat[ln*16 + k];
    #pragma unroll
    for (int u = 0; u < 8; ++u){
      int s0 = wv*16 + u*2, s1 = s0 + 1;
      const float4* e0p = (const float4*)(enc + (size_t)s0*H) + ln*4;
      const float4* e1p = (const float4*)(enc + (size_t)s1*H) + ln*4;
      float4 e0[4], e1[4];
      #pragma unroll
      for (int k = 0; k < 4; ++k) e0[k] = e0p[k];
      #pragma unroll
      for (int k = 0; k < 4; ++k) e1[k] = e1p[k];
      float acc0 = dot4(e0[0], hv) + dot4(e0[1], hv+4) + dot4(e0[2], hv+8) + dot4(e0[3], hv+12);
      float acc1 = dot4(e1[0], hv) + dot4(e1[1], hv+4) + dot4(e1[2], hv+8) + dot4(e1[3], hv+12);
      acc0 = wave_sum(acc0);
      acc1 = wave_sum(acc1);
      if (ln == 0){ sc[s0] = acc0; sc[s1] = acc1; }
    }
  }
  __syncthreads();

  // phase 3: softmax over 128 scores — wave 0 only, shuffle reduce
  if (wv == 0){
    float v0 = sc[ln], v1 = sc[ln + 64];
    float m = wave_max(fmaxf(v0, v1));
    float e0 = expf(v0 - m), e1 = expf(v1 - m);
    float S = wave_sum(e0 + e1);
    pw[ln]      = e0 / S;
    pw[ln + 64] = e1 / S;
  }
  __syncthreads();

  // phase 4: ctx[j] = sum_s pw[s] * enc[s][j]; 512 threads x 2 contiguous cols
  {
    float a0 = 0.f, a1 = 0.f;
    const float2* eb = (const float2*)enc + tid;   // cols [tid*2, tid*2+2)
    #pragma unroll 8
    for (int s = 0; s < SQ; ++s){
      float2 e = eb[(size_t)s*(H/2)];
      float w = pw[s];
      a0 += w*e.x; a1 += w*e.y;
    }
    concat[H + tid*2 + 0] = a0;
    concat[H + tid*2 + 1] = a1;
  }
  __syncthreads();

  // phase 5: FC rows. 8 waves x 4 iterations x 4 rows each; all 32 float4 row
  // loads of an iteration issued back-to-back (deep MLP). Rows >= FROWS are
  // clamped on load and guarded on write.
  {
    float cv[32];
    #pragma unroll
    for (int k = 0; k < 8; ++k)
      #pragma unroll
      for (int m = 0; m < 4; ++m)
        cv[k*4 + m] = concat[k*256 + ln*4 + m];

    #pragma unroll
    for (int it = 0; it < 4; ++it){
      int l = wv*4 + it*32;                  // base row 0..124 (multiples of 4)
      int c0 = l,     c1 = l+1, c2 = l+2, c3 = l+3;
      if (c1 > FROWS-1) c1 = FROWS-1;        // clamp loads (writes guarded below)
      if (c2 > FROWS-1) c2 = FROWS-1;
      if (c3 > FROWS-1) c3 = FROWS-1;
      const float4* p0 = (const float4*)(W_fc + (size_t)(b*FROWS + c0)*2048) + ln;
      const float4* p1 = (const float4*)(W_fc + (size_t)(b*FROWS + c1)*2048) + ln;
      const float4* p2 = (const float4*)(W_fc + (size_t)(b*FROWS + c2)*2048) + ln;
      const float4* p3 = (const float4*)(W_fc + (size_t)(b*FROWS + c3)*2048) + ln;
      float4 w0[8], w1[8], w2[8], w3[8];
      #pragma unroll
      for (int k = 0; k < 8; ++k) w0[k] = p0[(size_t)k*64];
      #pragma unroll
      for (int k = 0; k < 8; ++k) w1[k] = p1[(size_t)k*64];
      #pragma unroll
      for (int k = 0; k < 8; ++k) w2[k] = p2[(size_t)k*64];
      #pragma unroll
      for (int k = 0; k < 8; ++k) w3[k] = p3[(size_t)k*64];
      float a0 = 0.f, a1 = 0.f, a2 = 0.f, a3 = 0.f;
      #pragma unroll
      for (int k = 0; k < 8; ++k){
        a0 += dot4(w0[k], cv + k*4);
        a1 += dot4(w1[k], cv + k*4);
        a2 += dot4(w2[k], cv + k*4);
        a3 += dot4(w3[k], cv + k*4);
      }
      a0 = wave_sum(a0);
      a1 = wave_sum(a1);
      a2 = wave_sum(a2);
      a3 = wave_sum(a3);
      if (ln == 0){
        int row = b*FROWS + l;
        {            float x = a0 + b_fc[row];     ws->logits[row]   = x; lg[l]   = x; }
        if (l+1 < FROWS){ float x = a1 + b_fc[row+1]; ws->logits[row+1] = x; lg[l+1] = x; }
        if (l+2 < FROWS){ float x = a2 + b_fc[row+2]; ws->logits[row+2] = x; lg[l+2] = x; }
        if (l+3 < FROWS){ float x = a3 + b_fc[row+3]; ws->logits[row+3] = x; lg[l+3] = x; }
      }
    }
  }
  __syncthreads();

  // phase 6: block-local max / sumexp / packed argmax key — wave 0 only
  if (wv == 0){
    float v0 = (ln < FROWS)      ? lg[ln]      : NEG_BIG;
    float v1 = (ln + 64 < FROWS) ? lg[ln + 64] : NEG_BIG;
    float mb = wave_max(fmaxf(v0, v1));
    float e  = expf(v0 - mb) + expf(v1 - mb);   // NEG_BIG -> exp(-huge) = 0
    float sb = wave_sum(e);

    u64 k0 = 0ull, k1 = 0ull;
    if (ln < FROWS){
      u32 u = __float_as_uint(v0);
      u32 srt = (u >> 31) ? ~u : (u | 0x80000000u);
      k0 = ((u64)srt << 32) | (u32)(~(u32)(b*FROWS + ln));
    }
    if (ln + 64 < FROWS){
      u32 u = __float_as_uint(v1);
      u32 srt = (u >> 31) ? ~u : (u | 0x80000000u);
      k1 = ((u64)srt << 32) | (u32)(~(u32)(b*FROWS + ln + 64));
    }
    u64 key = wave_max_u64((k0 > k1) ? k0 : k1);

    if (ln == 0){
      ws->pmax[b] = mb;
      ws->psum[b] = sb;
      ws->pkey[b] = key;
    }
  }
}

extern "C" void kernel_launch(void* const* d_in, const int* in_sizes, int n_in,
                              void* d_out, int out_size, void* d_ws, size_t ws_size,
                              hipStream_t stream){
  const float* hn   = (const float*)d_in[0];
  const float* cn   = (const float*)d_in[1];
  const float* enc  = (const float*)d_in[2];
  const float* emb  = (const float*)d_in[3];
  const float* W_ih = (const float*)d_in[4];
  const float* W_hh = (const float*)d_in[5];
  const float* b_ih = (const float*)d_in[6];
  const float* b_hh = (const float*)d_in[7];
  const float* W_fc = (const float*)d_in[8];
  const float* b_fc = (const float*)d_in[9];
  float* out = (float*)d_out;
  WS* ws = (WS*)d_ws;
  if (ws_size < sizeof(WS)) return;  // needs ~160 KB

  k_init<<<1, NTI, 0, stream>>>(hn, cn, ws);
  for (int t = 0; t <= T; ++t){
    k_a<<<NB, NTA, 0, stream>>>(emb, W_ih, W_hh, b_ih, b_hh, ws, out, t);
    if (t < T) k_b<<<NB, NTB, 0, stream>>>(enc, W_fc, b_fc, ws, t);
  }
}